// Round 8
// baseline (377.481 us; speedup 1.0000x reference)
//
#include <hip/hip_runtime.h>
#include <math.h>

#define S_LEN   2048
#define D_MODEL 1024
#define N_HEADS 16
#define D_HEAD  64
#define D_MLP   4096
#define T_TOKENS 4096
// 0.125 (1/sqrt(64)) * log2(e): folds softmax scale + exp2-domain into Q
#define QSCALE_F 0.18033688011112042f

typedef __attribute__((ext_vector_type(8))) short short8;
typedef __attribute__((ext_vector_type(4))) float f32x4;
typedef unsigned short ushort_t;
typedef unsigned long long u64;

__device__ __forceinline__ ushort_t f2bf(float x) {
    unsigned int u = __float_as_uint(x);
    return (ushort_t)((u + 0x7FFFu + ((u >> 16) & 1u)) >> 16);
}

__device__ __forceinline__ float gelu_exact(float x) {
    return 0.5f * x * (1.0f + erff(x * 0.7071067811865476f));
}

__device__ __forceinline__ void gld_lds16(const void* g, void* l) {
    __builtin_amdgcn_global_load_lds(
        (const __attribute__((address_space(1))) unsigned int*)g,
        (__attribute__((address_space(3))) unsigned int*)l, 16, 0, 0);
}

// XCD band swizzle (requires gridDim.y == 32 m-tiles): blocks land on XCD ~ b%8,
// so make b&7 select a 4-m-tile band; the 32 blocks per XCD then share a 4MB
// L2-resident A-band and read B in k-lockstep (R7: FETCH 143->37MB).
__device__ __forceinline__ void swizzle_mn(int& m0, int& n0) {
    int gx = gridDim.x;
    int b = blockIdx.y * gx + blockIdx.x;
    int band = b & 7, t = b >> 3;
    n0 = (t % gx) * 128;
    m0 = (band * 4 + t / gx) * 128;
}

// LDS bank swizzle for GEMM tiles [row][32 ushorts]: chunk (row, part) lives at
// slot part ^ ((row>>1)&3). Unswizzled, fragment ds_read_b128 (16 rows x fixed
// 16B column) hits 2x4 banks = 8-way conflict (~2.94x, m136; R7 counter 4.19M).
// Swizzled: (row parity, part^..) tiles all 8 bank groups -> 2-way = free.
// 64/16-row offsets are 0 mod 4 after >>1, so staging swizzle depends only on tid.

// ---------------------------------------------------------------- LayerNorm (fp32 in, bf16 out)
__global__ __launch_bounds__(256) void ln_kernel(const float* __restrict__ x,
                                                 const float* __restrict__ w,
                                                 const float* __restrict__ b,
                                                 ushort_t* __restrict__ out) {
    int t = blockIdx.x;
    int tid = threadIdx.x;
    const float* xp = x + (size_t)t * D_MODEL;
    float4 v = *(const float4*)(xp + tid * 4);
    float s  = v.x + v.y + v.z + v.w;
    float sq = v.x*v.x + v.y*v.y + v.z*v.z + v.w*v.w;
    for (int o = 32; o; o >>= 1) {
        s  += __shfl_down(s, o, 64);
        sq += __shfl_down(sq, o, 64);
    }
    __shared__ float ss[4], ssq[4];
    if ((tid & 63) == 0) { ss[tid >> 6] = s; ssq[tid >> 6] = sq; }
    __syncthreads();
    float S  = ss[0] + ss[1] + ss[2] + ss[3];
    float SQ = ssq[0] + ssq[1] + ssq[2] + ssq[3];
    float mean = S * (1.0f / D_MODEL);
    float var  = SQ * (1.0f / D_MODEL) - mean * mean;
    float rstd = rsqrtf(var + 1e-5f);
    float4 wv = *(const float4*)(w + tid * 4);
    float4 bv = *(const float4*)(b + tid * 4);
    float ox = (v.x - mean) * rstd * wv.x + bv.x;
    float oy = (v.y - mean) * rstd * wv.y + bv.y;
    float oz = (v.z - mean) * rstd * wv.z + bv.z;
    float ow = (v.w - mean) * rstd * wv.w + bv.w;
    u64 pack = (u64)f2bf(ox) | ((u64)f2bf(oy) << 16) | ((u64)f2bf(oz) << 32) | ((u64)f2bf(ow) << 48);
    *(u64*)(out + (size_t)t * D_MODEL + tid * 4) = pack;
}

// ---------------------------------------------------------------- fp32 [R][C] -> bf16 [C][R]
__global__ __launch_bounds__(256) void transpose_f2b(const float* __restrict__ in,
                                                     long long inStride, int ldin,
                                                     ushort_t* __restrict__ out,
                                                     long long outStride, int ldout) {
    in  += (size_t)blockIdx.z * inStride;
    out += (size_t)blockIdx.z * outStride;
    __shared__ float t[32][33];
    int c0 = blockIdx.x * 32, r0 = blockIdx.y * 32;
    int tx = threadIdx.x, ty = threadIdx.y;   // 32 x 8
    #pragma unroll
    for (int i = 0; i < 32; i += 8)
        t[ty + i][tx] = in[(size_t)(r0 + ty + i) * ldin + c0 + tx];
    __syncthreads();
    #pragma unroll
    for (int i = 0; i < 32; i += 8)
        out[(size_t)(c0 + ty + i) * ldout + r0 + tx] = f2bf(t[tx][ty + i]);
}

// ---------------------------------------------------------------- bf16 [2048][64] -> [64][2048] per pair
__global__ __launch_bounds__(256) void tpose_b2b(const ushort_t* __restrict__ in,
                                                 ushort_t* __restrict__ out) {
    int pair = blockIdx.z;
    in  += (size_t)pair * (S_LEN * 64);
    out += (size_t)pair * (S_LEN * 64);
    __shared__ ushort_t t[32][33];
    int s0 = blockIdx.x * 32, d0 = blockIdx.y * 32;
    int tx = threadIdx.x, ty = threadIdx.y;  // 32 x 8
    #pragma unroll
    for (int i = 0; i < 32; i += 8)
        t[ty + i][tx] = in[(size_t)(s0 + ty + i) * 64 + d0 + tx];
    __syncthreads();
    #pragma unroll
    for (int i = 0; i < 32; i += 8)
        out[(size_t)(d0 + ty + i) * S_LEN + s0 + tx] = t[tx][ty + i];
}

// ---------------------------------------------------------------- QKV bias concat (3072)
__global__ __launch_bounds__(256) void qkv_bias_cat(const float* __restrict__ bq,
                                                    const float* __restrict__ bk,
                                                    const float* __restrict__ bv,
                                                    float* __restrict__ out) {
    int i = blockIdx.x * 256 + threadIdx.x;
    float v = (i < 1024) ? bq[i] : (i < 2048 ? bk[i - 1024] : bv[i - 2048]);
    out[i] = v;
}

// ---------------------------------------------------------------- bf16 MFMA GEMM v3 (bank-swizzled)
template<int OUT_MODE, bool DO_GELU, bool HAS_RES>
__global__ __launch_bounds__(256, 4) void mfma_gemm(
    const ushort_t* __restrict__ A, int lda,
    const ushort_t* __restrict__ Bt, int ldb,
    void* __restrict__ Cv, int ldc, int K,
    const float* __restrict__ bias,
    const float* __restrict__ res, int ldres) {

    __shared__ ushort_t As[2][128 * 32];
    __shared__ ushort_t Bs[2][128 * 32];

    int tid  = threadIdx.x;
    int lane = tid & 63;
    int m0, n0;
    swizzle_mn(m0, n0);
    int wave = tid >> 6;
    int wm = (wave & 1) * 64, wn = (wave >> 1) * 64;
    int quad = lane >> 4, l15 = lane & 15;

    int srow = tid >> 2;
    int skc  = (((tid & 3) ^ ((tid >> 3) & 3))) * 8;   // bank-swizzled k-part
    const ushort_t* Ap  = A  + (size_t)(m0 + srow)      * lda + skc;
    const ushort_t* Ap2 = A  + (size_t)(m0 + srow + 64) * lda + skc;
    const ushort_t* Bp  = Bt + (size_t)(n0 + srow)      * ldb + skc;
    const ushort_t* Bp2 = Bt + (size_t)(n0 + srow + 64) * ldb + skc;

    int fsw = (l15 >> 1) & 3;                          // fragment-read column swizzle

    f32x4 acc[4][4];
    #pragma unroll
    for (int i = 0; i < 4; ++i)
        #pragma unroll
        for (int j = 0; j < 4; ++j)
            acc[i][j] = (f32x4){0.f, 0.f, 0.f, 0.f};

    gld_lds16(Ap,  &As[0][tid * 8]);
    gld_lds16(Ap2, &As[0][(tid + 256) * 8]);
    gld_lds16(Bp,  &Bs[0][tid * 8]);
    gld_lds16(Bp2, &Bs[0][(tid + 256) * 8]);

    int niter = K >> 5;
    for (int j = 0; j < niter; ++j) {
        __syncthreads();
        int p = j & 1;
        if (j + 1 < niter) {
            int k1 = (j + 1) << 5;
            gld_lds16(Ap  + k1, &As[p ^ 1][tid * 8]);
            gld_lds16(Ap2 + k1, &As[p ^ 1][(tid + 256) * 8]);
            gld_lds16(Bp  + k1, &Bs[p ^ 1][tid * 8]);
            gld_lds16(Bp2 + k1, &Bs[p ^ 1][(tid + 256) * 8]);
        }
        short8 a[4], b[4];
        #pragma unroll
        for (int i = 0; i < 4; ++i) {
            a[i] = *(const short8*)&As[p][(wm + i * 16 + l15) * 32 + (quad ^ fsw) * 8];
            b[i] = *(const short8*)&Bs[p][(wn + i * 16 + l15) * 32 + (quad ^ fsw) * 8];
        }
        #pragma unroll
        for (int i = 0; i < 4; ++i)
            #pragma unroll
            for (int jj = 0; jj < 4; ++jj)
                acc[i][jj] = __builtin_amdgcn_mfma_f32_16x16x32_bf16(a[i], b[jj], acc[i][jj], 0, 0, 0);
    }

    #pragma unroll
    for (int i = 0; i < 4; ++i) {
        int rBase = m0 + wm + i * 16 + quad * 4;
        #pragma unroll
        for (int j = 0; j < 4; ++j) {
            int col = n0 + wn + j * 16 + l15;
            float bv = bias ? bias[col] : 0.f;
            #pragma unroll
            for (int r = 0; r < 4; ++r) {
                int rowg = rBase + r;
                float v = acc[i][j][r] + bv;
                if (DO_GELU) v = gelu_exact(v);
                if (HAS_RES) v += res[(size_t)rowg * ldres + col];
                if (OUT_MODE == 0)
                    ((float*)Cv)[(size_t)rowg * ldc + col] = v;
                else
                    ((ushort_t*)Cv)[(size_t)rowg * ldc + col] = f2bf(v);
            }
        }
    }
}

// ---------------------------------------------------------------- bf16 MFMA GEMM, intra-block split-K (bank-swizzled)
template<int OUT_MODE, bool DO_GELU, bool HAS_RES>
__global__ __launch_bounds__(512, 2) void mfma_gemm_sk(
    const ushort_t* __restrict__ A, int lda,
    const ushort_t* __restrict__ Bt, int ldb,
    void* __restrict__ Cv, int ldc, int K,
    const float* __restrict__ bias,
    const float* __restrict__ res, int ldres) {

    __shared__ ushort_t Smem[32768];    // 64 KB: [A: (g*2+p)*4096][B: +16384]; reused as f32 reduce
    #define SA_(g, p) (Smem + ((g) * 2 + (p)) * 4096)
    #define SB_(g, p) (Smem + 16384 + ((g) * 2 + (p)) * 4096)

    int tid  = threadIdx.x;
    int lane = tid & 63;
    int wave = tid >> 6;
    int g = wave >> 2, w = wave & 3;
    int m0, n0;
    swizzle_mn(m0, n0);
    int wm = (w & 1) * 64, wn = (w >> 1) * 64;
    int quad = lane >> 4, l15 = lane & 15;

    int lt = tid & 255;
    int srow = lt >> 2;
    int skc  = (((lt & 3) ^ ((lt >> 3) & 3))) * 8;
    int kbase = g * (K >> 1);
    const ushort_t* Ap  = A  + (size_t)(m0 + srow)      * lda + kbase + skc;
    const ushort_t* Ap2 = A  + (size_t)(m0 + srow + 64) * lda + kbase + skc;
    const ushort_t* Bp  = Bt + (size_t)(n0 + srow)      * ldb + kbase + skc;
    const ushort_t* Bp2 = Bt + (size_t)(n0 + srow + 64) * ldb + kbase + skc;

    int fsw = (l15 >> 1) & 3;

    f32x4 acc[4][4];
    #pragma unroll
    for (int i = 0; i < 4; ++i)
        #pragma unroll
        for (int j = 0; j < 4; ++j)
            acc[i][j] = (f32x4){0.f, 0.f, 0.f, 0.f};

    gld_lds16(Ap,  SA_(g, 0) + lt * 8);
    gld_lds16(Ap2, SA_(g, 0) + (lt + 256) * 8);
    gld_lds16(Bp,  SB_(g, 0) + lt * 8);
    gld_lds16(Bp2, SB_(g, 0) + (lt + 256) * 8);

    int niter = K >> 6;                 // each group: K/2 over BK=32
    for (int j = 0; j < niter; ++j) {
        __syncthreads();
        int p = j & 1;
        if (j + 1 < niter) {
            int k1 = (j + 1) << 5;
            gld_lds16(Ap  + k1, SA_(g, p ^ 1) + lt * 8);
            gld_lds16(Ap2 + k1, SA_(g, p ^ 1) + (lt + 256) * 8);
            gld_lds16(Bp  + k1, SB_(g, p ^ 1) + lt * 8);
            gld_lds16(Bp2 + k1, SB_(g, p ^ 1) + (lt + 256) * 8);
        }
        const ushort_t* Ac = SA_(g, p);
        const ushort_t* Bc = SB_(g, p);
        short8 a[4], b[4];
        #pragma unroll
        for (int i = 0; i < 4; ++i) {
            a[i] = *(const short8*)(Ac + (wm + i * 16 + l15) * 32 + (quad ^ fsw) * 8);
            b[i] = *(const short8*)(Bc + (wn + i * 16 + l15) * 32 + (quad ^ fsw) * 8);
        }
        #pragma unroll
        for (int i = 0; i < 4; ++i)
            #pragma unroll
            for (int jj = 0; jj < 4; ++jj)
                acc[i][jj] = __builtin_amdgcn_mfma_f32_16x16x32_bf16(a[i], b[jj], acc[i][jj], 0, 0, 0);
    }

    // cross-group reduction through the dead staging LDS
    __syncthreads();
    float* R = (float*)Smem;
    if (g == 1) {
        #pragma unroll
        for (int i = 0; i < 4; ++i)
            #pragma unroll
            for (int j = 0; j < 4; ++j)
                *(f32x4*)&R[(((w * 16 + i * 4 + j) * 64) + lane) * 4] = acc[i][j];
    }
    __syncthreads();
    if (g == 0) {
        #pragma unroll
        for (int i = 0; i < 4; ++i) {
            int rBase = m0 + wm + i * 16 + quad * 4;
            #pragma unroll
            for (int j = 0; j < 4; ++j) {
                f32x4 other = *(const f32x4*)&R[(((w * 16 + i * 4 + j) * 64) + lane) * 4];
                int col = n0 + wn + j * 16 + l15;
                float bv = bias ? bias[col] : 0.f;
                #pragma unroll
                for (int r = 0; r < 4; ++r) {
                    int rowg = rBase + r;
                    float v = acc[i][j][r] + other[r] + bv;
                    if (DO_GELU) v = gelu_exact(v);
                    if (HAS_RES) v += res[(size_t)rowg * ldres + col];
                    if (OUT_MODE == 0)
                        ((float*)Cv)[(size_t)rowg * ldc + col] = v;
                    else
                        ((ushort_t*)Cv)[(size_t)rowg * ldc + col] = f2bf(v);
                }
            }
        }
    }
    #undef SA_
    #undef SB_
}

// ---------------------------------------------------------------- QKV GEMM v3: bf16 out, head-major, Q pre-scaled
__global__ __launch_bounds__(256, 4) void mfma_gemm_qkv(
    const ushort_t* __restrict__ A, const ushort_t* __restrict__ Bt,
    ushort_t* __restrict__ Qh, ushort_t* __restrict__ Kh, ushort_t* __restrict__ Vh,
    const float* __restrict__ bias) {

    const int lda = 1024, ldb = 1024, K = 1024;
    __shared__ ushort_t As[2][128 * 32];
    __shared__ ushort_t Bs[2][128 * 32];

    int tid  = threadIdx.x;
    int lane = tid & 63;
    int m0, n0;
    swizzle_mn(m0, n0);
    int wave = tid >> 6;
    int wm = (wave & 1) * 64, wn = (wave >> 1) * 64;
    int quad = lane >> 4, l15 = lane & 15;

    int srow = tid >> 2;
    int skc  = (((tid & 3) ^ ((tid >> 3) & 3))) * 8;
    const ushort_t* Ap  = A  + (size_t)(m0 + srow)      * lda + skc;
    const ushort_t* Ap2 = A  + (size_t)(m0 + srow + 64) * lda + skc;
    const ushort_t* Bp  = Bt + (size_t)(n0 + srow)      * ldb + skc;
    const ushort_t* Bp2 = Bt + (size_t)(n0 + srow + 64) * ldb + skc;

    int fsw = (l15 >> 1) & 3;

    f32x4 acc[4][4];
    #pragma unroll
    for (int i = 0; i < 4; ++i)
        #pragma unroll
        for (int j = 0; j < 4; ++j)
            acc[i][j] = (f32x4){0.f, 0.f, 0.f, 0.f};

    gld_lds16(Ap,  &As[0][tid * 8]);
    gld_lds16(Ap2, &As[0][(tid + 256) * 8]);
    gld_lds16(Bp,  &Bs[0][tid * 8]);
    gld_lds16(Bp2, &Bs[0][(tid + 256) * 8]);

    const int niter = K >> 5;
    for (int j = 0; j < niter; ++j) {
        __syncthreads();
        int p = j & 1;
        if (j + 1 < niter) {
            int k1 = (j + 1) << 5;
            gld_lds16(Ap  + k1, &As[p ^ 1][tid * 8]);
            gld_lds16(Ap2 + k1, &As[p ^ 1][(tid + 256) * 8]);
            gld_lds16(Bp  + k1, &Bs[p ^ 1][tid * 8]);
            gld_lds16(Bp2 + k1, &Bs[p ^ 1][(tid + 256) * 8]);
        }
        short8 a[4], b[4];
        #pragma unroll
        for (int i = 0; i < 4; ++i) {
            a[i] = *(const short8*)&As[p][(wm + i * 16 + l15) * 32 + (quad ^ fsw) * 8];
            b[i] = *(const short8*)&Bs[p][(wn + i * 16 + l15) * 32 + (quad ^ fsw) * 8];
        }
        #pragma unroll
        for (int i = 0; i < 4; ++i)
            #pragma unroll
            for (int jj = 0; jj < 4; ++jj)
                acc[i][jj] = __builtin_amdgcn_mfma_f32_16x16x32_bf16(a[i], b[jj], acc[i][jj], 0, 0, 0);
    }

    #pragma unroll
    for (int i = 0; i < 4; ++i) {
        int rBase = m0 + wm + i * 16 + quad * 4;
        #pragma unroll
        for (int j = 0; j < 4; ++j) {
            int col = n0 + wn + j * 16 + l15;
            int sel = col >> 10;                    // 0=Q,1=K,2=V
            int h   = (col >> 6) & 15;
            int dh  = col & 63;
            ushort_t* dst = (sel == 0) ? Qh : (sel == 1 ? Kh : Vh);
            float sc = (sel == 0) ? QSCALE_F : 1.0f;
            float bv = bias[col];
            #pragma unroll
            for (int r = 0; r < 4; ++r) {
                int rowg = rBase + r;               // token
                int bb = rowg >> 11, s = rowg & 2047;
                float v = (acc[i][j][r] + bv) * sc;
                dst[((size_t)(bb * 16 + h) * S_LEN + s) * 64 + dh] = f2bf(v);
            }
        }
    }
}

// ---------------------------------------------------------------- fused flash attention v2 (unchanged)
__global__ __launch_bounds__(256, 4) void flash_kernel(
    const ushort_t* __restrict__ Qh, const ushort_t* __restrict__ Kh,
    const ushort_t* __restrict__ Vt, ushort_t* __restrict__ Z) {

    __shared__ ushort_t Klds[2][64 * 64];
    __shared__ ushort_t Vlds[2][64 * 64];
    __shared__ ushort_t Plds[4][16 * 64];

    int pair = blockIdx.x;                    // 0..31  (pair%8 keys XCD -> 2MB KV per XCD L2)
    int qt   = blockIdx.y;                    // 0..31
    int q0   = qt * 64;
    int tid = threadIdx.x, lane = tid & 63, wave = tid >> 6;
    int quad = lane >> 4, l15 = lane & 15;

    const ushort_t* Qbase = Qh + (size_t)pair * (S_LEN * 64);
    const ushort_t* Kbase = Kh + (size_t)pair * (S_LEN * 64);
    const ushort_t* Vbase = Vt + (size_t)pair * (S_LEN * 64);
    ushort_t* Qstage = &Plds[0][0];

    #pragma unroll
    for (int n = 0; n < 2; ++n) {
        int c = tid + n * 256;
        int row = c >> 3, part = c & 7;
        gld_lds16(Qbase + (size_t)(q0 + row) * 64 + ((part ^ (row & 7)) * 8), Qstage + c * 8);
    }
    __syncthreads();
    short8 qa[2];
    #pragma unroll
    for (int h = 0; h < 2; ++h) {
        int row = wave * 16 + l15;
        int part = (h * 4 + quad) ^ (row & 7);
        qa[h] = *(const short8*)(Qstage + row * 64 + part * 8);
    }

    f32x4 ls = (f32x4){0.f, 0.f, 0.f, 0.f};
    f32x4 zacc[4];
    #pragma unroll
    for (int dht = 0; dht < 4; ++dht) zacc[dht] = (f32x4){0.f, 0.f, 0.f, 0.f};

    #pragma unroll
    for (int n = 0; n < 2; ++n) {
        int c = tid + n * 256;
        int row = c >> 3, part = c & 7;
        int gp = (part ^ (row & 7)) * 8;
        gld_lds16(Kbase + (size_t)row * 64 + gp, &Klds[0][0] + c * 8);
        gld_lds16(Vbase + (size_t)row * S_LEN + gp, &Vlds[0][0] + c * 8);
    }

    for (int j = 0; j <= qt; ++j) {
        __syncthreads();
        int p = j & 1;
        if (j < qt) {
            int k1 = (j + 1) * 64;
            #pragma unroll
            for (int n = 0; n < 2; ++n) {
                int c = tid + n * 256;
                int row = c >> 3, part = c & 7;
                int gp = (part ^ (row & 7)) * 8;
                gld_lds16(Kbase + (size_t)(k1 + row) * 64 + gp, &Klds[p ^ 1][0] + c * 8);
                gld_lds16(Vbase + (size_t)row * S_LEN + k1 + gp, &Vlds[p ^ 1][0] + c * 8);
            }
        }
        const ushort_t* Kc = &Klds[p][0];
        const ushort_t* Vc = &Vlds[p][0];

        f32x4 s[4];
        #pragma unroll
        for (int jt = 0; jt < 4; ++jt) {
            int krow = jt * 16 + l15;
            int sw = krow & 7;
            short8 kb0 = *(const short8*)(Kc + krow * 64 + ((quad ^ sw) * 8));
            short8 kb1 = *(const short8*)(Kc + krow * 64 + (((quad + 4) ^ sw) * 8));
            f32x4 t = __builtin_amdgcn_mfma_f32_16x16x32_bf16(qa[0], kb0,
                        (f32x4){0.f, 0.f, 0.f, 0.f}, 0, 0, 0);
            s[jt] = __builtin_amdgcn_mfma_f32_16x16x32_bf16(qa[1], kb1, t, 0, 0, 0);
        }

        if (j == qt) {
            #pragma unroll
            for (int jt = 0; jt < 4; ++jt) {
                int kc = jt * 16 + l15;
                int qr = wave * 16 + quad * 4;
                #pragma unroll
                for (int r = 0; r < 4; ++r)
                    if (kc > qr + r) s[jt][r] = -1e30f;
            }
        }

        #pragma unroll
        for (int jt = 0; jt < 4; ++jt) {
            #pragma unroll
            for (int r = 0; r < 4; ++r) {
                float pv = exp2f(s[jt][r]);
                s[jt][r] = pv;
                ls[r] += pv;
            }
        }

        ushort_t* Pw = &Plds[wave][0];
        #pragma unroll
        for (int jt = 0; jt < 4; ++jt) {
            int col = jt * 16 + l15;
            int cp = col >> 3, ci = col & 7;
            #pragma unroll
            for (int r = 0; r < 4; ++r) {
                int prow = quad * 4 + r;
                Pw[prow * 64 + ((cp ^ (prow & 7)) * 8) + ci] = f2bf(s[jt][r]);
            }
        }

        #pragma unroll
        for (int kc = 0; kc < 2; ++kc) {
            int prow = l15;
            short8 pa = *(const short8*)(Pw + prow * 64 + ((((kc * 4 + quad) ^ (prow & 7))) * 8));
            #pragma unroll
            for (int dht = 0; dht < 4; ++dht) {
                int vrow = dht * 16 + l15;
                short8 vb = *(const short8*)(Vc + vrow * 64 + ((((kc * 4 + quad) ^ (vrow & 7))) * 8));
                zacc[dht] = __builtin_amdgcn_mfma_f32_16x16x32_bf16(pa, vb, zacc[dht], 0, 0, 0);
            }
        }
    }

    #pragma unroll
    for (int d = 1; d < 16; d <<= 1) {
        ls[0] += __shfl_xor(ls[0], d, 64);
        ls[1] += __shfl_xor(ls[1], d, 64);
        ls[2] += __shfl_xor(ls[2], d, 64);
        ls[3] += __shfl_xor(ls[3], d, 64);
    }
    int bb = pair >> 4, h = pair & 15;
    #pragma unroll
    for (int r = 0; r < 4; ++r) {
        int qrow = q0 + wave * 16 + quad * 4 + r;
        size_t tok = (size_t)bb * S_LEN + qrow;
        float inv = 1.0f / ls[r];
        #pragma unroll
        for (int dht = 0; dht < 4; ++dht)
            Z[tok * D_MODEL + h * 64 + dht * 16 + l15] = f2bf(zacc[dht][r] * inv);
    }
}

// ---------------------------------------------------------------- launch
extern "C" void kernel_launch(void* const* d_in, const int* in_sizes, int n_in,
                              void* d_out, int out_size, void* d_ws, size_t ws_size,
                              hipStream_t stream) {
    const float* resid_pre = (const float*)d_in[0];
    const float* ln1_w = (const float*)d_in[1];
    const float* ln1_b = (const float*)d_in[2];
    const float* W_Q   = (const float*)d_in[3];
    const float* b_Q   = (const float*)d_in[4];
    const float* W_K   = (const float*)d_in[5];
    const float* b_K   = (const float*)d_in[6];
    const float* W_V   = (const float*)d_in[7];
    const float* b_V   = (const float*)d_in[8];
    const float* W_O   = (const float*)d_in[9];
    const float* b_O   = (const float*)d_in[10];
    const float* ln2_w = (const float*)d_in[11];
    const float* ln2_b = (const float*)d_in[12];
    const float* W_in  = (const float*)d_in[13];
    const float* b_in  = (const float*)d_in[14];
    const float* W_out = (const float*)d_in[15];
    const float* b_out = (const float*)d_in[16];
    float* out = (float*)d_out;
    char* W = (char*)d_ws;

    const size_t MB = 1u << 20;
    ushort_t* Qh     = (ushort_t*)(W + 0 * MB);      // [32][2048][64]  8MB
    ushort_t* Kh     = (ushort_t*)(W + 8 * MB);      // 8MB
    ushort_t* Vh     = (ushort_t*)(W + 16 * MB);     // 8MB
    ushort_t* Vt     = (ushort_t*)(W + 24 * MB);     // [32][64][2048]  8MB
    ushort_t* Zbf    = (ushort_t*)(W + 32 * MB);     // [4096][1024]    8MB
    ushort_t* LN1a   = (ushort_t*)(W + 40 * MB);     // 8MB
    ushort_t* Wqkv   = (ushort_t*)(W + 48 * MB);     // [3072][1024]    6MB
    ushort_t* Wo_t   = (ushort_t*)(W + 54 * MB);     // 2MB
    ushort_t* Win_t  = (ushort_t*)(W + 56 * MB);     // 8MB
    ushort_t* Wout_t = (ushort_t*)(W + 64 * MB);     // 8MB
    ushort_t* LN2a   = (ushort_t*)(W + 72 * MB);     // 8MB
    ushort_t* MLPh   = (ushort_t*)(W + 80 * MB);     // [4096][4096]    32MB
    float*    MID    = (float*)  (W + 112 * MB);     // 16MB
    float*    qbias  = (float*)  (W + 128 * MB);     // 12KB

    const size_t M1 = 1u << 20;
    dim3 tb(32, 8);

    // ---- weight prep + LN1 ----
    transpose_f2b<<<dim3(2, 32, 16), tb, 0, stream>>>(W_Q, 65536, 64, Wqkv,          65536, 1024);
    transpose_f2b<<<dim3(2, 32, 16), tb, 0, stream>>>(W_K, 65536, 64, Wqkv + 1 * M1, 65536, 1024);
    transpose_f2b<<<dim3(2, 32, 16), tb, 0, stream>>>(W_V, 65536, 64, Wqkv + 2 * M1, 65536, 1024);
    qkv_bias_cat<<<12, 256, 0, stream>>>(b_Q, b_K, b_V, qbias);
    ln_kernel<<<T_TOKENS, 256, 0, stream>>>(resid_pre, ln1_w, ln1_b, LN1a);

    // ---- QKV projection -> head-major bf16 (Q pre-scaled) ----
    mfma_gemm_qkv<<<dim3(24, 32), 256, 0, stream>>>(LN1a, Wqkv, Qh, Kh, Vh, qbias);
    tpose_b2b<<<dim3(64, 2, 32), tb, 0, stream>>>(Vh, Vt);

    // ---- fused flash attention ----
    flash_kernel<<<dim3(32, 32), 256, 0, stream>>>(Qh, Kh, Vt, Zbf);

    // ---- O-proj + residual -> MID (split-K, 512 thr) ----
    transpose_f2b<<<dim3(32, 32, 1), tb, 0, stream>>>(W_O, 0, 1024, Wo_t, 0, 1024);
    mfma_gemm_sk<0, false, true><<<dim3(8, 32), 512, 0, stream>>>(
        Zbf, 1024, Wo_t, 1024, MID, 1024, 1024, b_O, resid_pre, 1024);

    // ---- LN2 + MLP ----
    ln_kernel<<<T_TOKENS, 256, 0, stream>>>(MID, ln2_w, ln2_b, LN2a);
    transpose_f2b<<<dim3(128, 32, 1), tb, 0, stream>>>(W_in,  0, 4096, Win_t,  0, 1024);
    transpose_f2b<<<dim3(32, 128, 1), tb, 0, stream>>>(W_out, 0, 1024, Wout_t, 0, 4096);
    mfma_gemm<1, true, false><<<dim3(32, 32), 256, 0, stream>>>(
        LN2a, 1024, Win_t, 1024, MLPh, 4096, 1024, b_in, nullptr, 0);
    mfma_gemm_sk<0, false, true><<<dim3(8, 32), 512, 0, stream>>>(
        MLPh, 4096, Wout_t, 4096, out, 1024, 4096, b_out, MID, 1024);
}

// Round 9
// 343.454 us; speedup vs baseline: 1.0991x; 1.0991x over previous
//
#include <hip/hip_runtime.h>
#include <math.h>

#define S_LEN   2048
#define D_MODEL 1024
#define N_HEADS 16
#define D_HEAD  64
#define D_MLP   4096
#define T_TOKENS 4096
// 0.125 (1/sqrt(64)) * log2(e): folds softmax scale + exp2-domain into Q
#define QSCALE_F 0.18033688011112042f

typedef __attribute__((ext_vector_type(8))) short short8;
typedef __attribute__((ext_vector_type(4))) float f32x4;
typedef unsigned short ushort_t;
typedef unsigned long long u64;

__device__ __forceinline__ ushort_t f2bf(float x) {
    unsigned int u = __float_as_uint(x);
    return (ushort_t)((u + 0x7FFFu + ((u >> 16) & 1u)) >> 16);
}
__device__ __forceinline__ float bf2f(ushort_t x) {
    unsigned int u = ((unsigned int)x) << 16;
    return __uint_as_float(u);
}

__device__ __forceinline__ float gelu_exact(float x) {
    return 0.5f * x * (1.0f + erff(x * 0.7071067811865476f));
}

__device__ __forceinline__ void gld_lds16(const void* g, void* l) {
    __builtin_amdgcn_global_load_lds(
        (const __attribute__((address_space(1))) unsigned int*)g,
        (__attribute__((address_space(3))) unsigned int*)l, 16, 0, 0);
}

// XCD band swizzle (R7: FETCH 143->37MB on MLP GEMMs)
__device__ __forceinline__ void swizzle_mn(int& m0, int& n0) {
    int gx = gridDim.x;
    int b = blockIdx.y * gx + blockIdx.x;
    int band = b & 7, t = b >> 3;
    n0 = (t % gx) * 128;
    m0 = (band * 4 + t / gx) * 128;
}

// ---------------------------------------------------------------- LayerNorm (fp32 in, bf16 out)
__global__ __launch_bounds__(256) void ln_kernel(const float* __restrict__ x,
                                                 const float* __restrict__ w,
                                                 const float* __restrict__ b,
                                                 ushort_t* __restrict__ out) {
    int t = blockIdx.x;
    int tid = threadIdx.x;
    const float* xp = x + (size_t)t * D_MODEL;
    float4 v = *(const float4*)(xp + tid * 4);
    float s  = v.x + v.y + v.z + v.w;
    float sq = v.x*v.x + v.y*v.y + v.z*v.z + v.w*v.w;
    for (int o = 32; o; o >>= 1) {
        s  += __shfl_down(s, o, 64);
        sq += __shfl_down(sq, o, 64);
    }
    __shared__ float ss[4], ssq[4];
    if ((tid & 63) == 0) { ss[tid >> 6] = s; ssq[tid >> 6] = sq; }
    __syncthreads();
    float S  = ss[0] + ss[1] + ss[2] + ss[3];
    float SQ = ssq[0] + ssq[1] + ssq[2] + ssq[3];
    float mean = S * (1.0f / D_MODEL);
    float var  = SQ * (1.0f / D_MODEL) - mean * mean;
    float rstd = rsqrtf(var + 1e-5f);
    float4 wv = *(const float4*)(w + tid * 4);
    float4 bv = *(const float4*)(b + tid * 4);
    float ox = (v.x - mean) * rstd * wv.x + bv.x;
    float oy = (v.y - mean) * rstd * wv.y + bv.y;
    float oz = (v.z - mean) * rstd * wv.z + bv.z;
    float ow = (v.w - mean) * rstd * wv.w + bv.w;
    u64 pack = (u64)f2bf(ox) | ((u64)f2bf(oy) << 16) | ((u64)f2bf(oz) << 32) | ((u64)f2bf(ow) << 48);
    *(u64*)(out + (size_t)t * D_MODEL + tid * 4) = pack;
}

// ---------------------------------------------------------------- LayerNorm (bf16 in, bf16 out)
__global__ __launch_bounds__(256) void ln_kernel_b(const ushort_t* __restrict__ x,
                                                   const float* __restrict__ w,
                                                   const float* __restrict__ b,
                                                   ushort_t* __restrict__ out) {
    int t = blockIdx.x;
    int tid = threadIdx.x;
    const ushort_t* xp = x + (size_t)t * D_MODEL;
    u64 pk = *(const u64*)(xp + tid * 4);
    float vx = bf2f((ushort_t)(pk & 0xffff));
    float vy = bf2f((ushort_t)((pk >> 16) & 0xffff));
    float vz = bf2f((ushort_t)((pk >> 32) & 0xffff));
    float vw = bf2f((ushort_t)(pk >> 48));
    float s  = vx + vy + vz + vw;
    float sq = vx*vx + vy*vy + vz*vz + vw*vw;
    for (int o = 32; o; o >>= 1) {
        s  += __shfl_down(s, o, 64);
        sq += __shfl_down(sq, o, 64);
    }
    __shared__ float ss[4], ssq[4];
    if ((tid & 63) == 0) { ss[tid >> 6] = s; ssq[tid >> 6] = sq; }
    __syncthreads();
    float S  = ss[0] + ss[1] + ss[2] + ss[3];
    float SQ = ssq[0] + ssq[1] + ssq[2] + ssq[3];
    float mean = S * (1.0f / D_MODEL);
    float var  = SQ * (1.0f / D_MODEL) - mean * mean;
    float rstd = rsqrtf(var + 1e-5f);
    float4 wv = *(const float4*)(w + tid * 4);
    float4 bv = *(const float4*)(b + tid * 4);
    float ox = (vx - mean) * rstd * wv.x + bv.x;
    float oy = (vy - mean) * rstd * wv.y + bv.y;
    float oz = (vz - mean) * rstd * wv.z + bv.z;
    float ow = (vw - mean) * rstd * wv.w + bv.w;
    u64 pack = (u64)f2bf(ox) | ((u64)f2bf(oy) << 16) | ((u64)f2bf(oz) << 32) | ((u64)f2bf(ow) << 48);
    *(u64*)(out + (size_t)t * D_MODEL + tid * 4) = pack;
}

// ---------------------------------------------------------------- fused weight prep: all fp32->bf16 transposes + qkv bias
// flat blocks: [0,3072) WQ/WK/WV, [3072,4096) WO, [4096,8192) Win, [8192,12288) Wout, [12288,12300) bias
__global__ __launch_bounds__(256) void prep_weights(
    const float* __restrict__ Wq, const float* __restrict__ Wk, const float* __restrict__ Wv,
    const float* __restrict__ Wo, const float* __restrict__ Wi, const float* __restrict__ Wu,
    const float* __restrict__ bq, const float* __restrict__ bk, const float* __restrict__ bv,
    ushort_t* __restrict__ wqkv, ushort_t* __restrict__ wo_t,
    ushort_t* __restrict__ win_t, ushort_t* __restrict__ wout_t,
    float* __restrict__ qbias) {
    int blk = blockIdx.x;
    if (blk >= 12288) {
        int i = (blk - 12288) * 256 + threadIdx.x;
        float v = (i < 1024) ? bq[i] : (i < 2048 ? bk[i - 1024] : bv[i - 2048]);
        qbias[i] = v;
        return;
    }
    int tx = threadIdx.x & 31, ty = threadIdx.x >> 5;   // 32 x 8
    const float* in; ushort_t* out; int ldin, ldout, bx, by;
    if (blk < 3072) {
        int w = blk >> 10, r = blk & 1023;
        int z = r >> 6; r &= 63;
        bx = r & 1; by = r >> 1;
        in  = (w == 0 ? Wq : (w == 1 ? Wk : Wv)) + (size_t)z * 65536;
        out = wqkv + (size_t)w * (1u << 20) + (size_t)z * 65536;
        ldin = 64; ldout = 1024;
    } else if (blk < 4096) {
        int r = blk - 3072; bx = r & 31; by = r >> 5;
        in = Wo; out = wo_t; ldin = 1024; ldout = 1024;
    } else if (blk < 8192) {
        int r = blk - 4096; bx = r & 127; by = r >> 7;
        in = Wi; out = win_t; ldin = 4096; ldout = 1024;
    } else {
        int r = blk - 8192; bx = r & 31; by = r >> 5;
        in = Wu; out = wout_t; ldin = 1024; ldout = 4096;
    }
    __shared__ float t[32][33];
    int c0 = bx * 32, r0 = by * 32;
    #pragma unroll
    for (int i = 0; i < 32; i += 8)
        t[ty + i][tx] = in[(size_t)(r0 + ty + i) * ldin + c0 + tx];
    __syncthreads();
    #pragma unroll
    for (int i = 0; i < 32; i += 8)
        out[(size_t)(c0 + ty + i) * ldout + r0 + tx] = f2bf(t[tx][ty + i]);
}

// ---------------------------------------------------------------- bf16 [2048][64] -> [64][2048] per pair
__global__ __launch_bounds__(256) void tpose_b2b(const ushort_t* __restrict__ in,
                                                 ushort_t* __restrict__ out) {
    int pair = blockIdx.z;
    in  += (size_t)pair * (S_LEN * 64);
    out += (size_t)pair * (S_LEN * 64);
    __shared__ ushort_t t[32][33];
    int s0 = blockIdx.x * 32, d0 = blockIdx.y * 32;
    int tx = threadIdx.x, ty = threadIdx.y;  // 32 x 8
    #pragma unroll
    for (int i = 0; i < 32; i += 8)
        t[ty + i][tx] = in[(size_t)(s0 + ty + i) * 64 + d0 + tx];
    __syncthreads();
    #pragma unroll
    for (int i = 0; i < 32; i += 8)
        out[(size_t)(d0 + ty + i) * S_LEN + s0 + tx] = t[tx][ty + i];
}

// ---------------------------------------------------------------- bf16 MFMA GEMM v3 (256 thr, BK=32, bank-swizzled)
// RES_MODE: 0 none, 1 fp32, 2 bf16
template<int OUT_MODE, bool DO_GELU, int RES_MODE>
__global__ __launch_bounds__(256, 4) void mfma_gemm(
    const ushort_t* __restrict__ A, int lda,
    const ushort_t* __restrict__ Bt, int ldb,
    void* __restrict__ Cv, int ldc, int K,
    const float* __restrict__ bias,
    const void* __restrict__ res, int ldres) {

    __shared__ ushort_t As[2][128 * 32];
    __shared__ ushort_t Bs[2][128 * 32];

    int tid  = threadIdx.x;
    int lane = tid & 63;
    int m0, n0;
    swizzle_mn(m0, n0);
    int wave = tid >> 6;
    int wm = (wave & 1) * 64, wn = (wave >> 1) * 64;
    int quad = lane >> 4, l15 = lane & 15;

    int srow = tid >> 2;
    int skc  = (((tid & 3) ^ ((tid >> 3) & 3))) * 8;   // bank-swizzled k-part
    const ushort_t* Ap  = A  + (size_t)(m0 + srow)      * lda + skc;
    const ushort_t* Ap2 = A  + (size_t)(m0 + srow + 64) * lda + skc;
    const ushort_t* Bp  = Bt + (size_t)(n0 + srow)      * ldb + skc;
    const ushort_t* Bp2 = Bt + (size_t)(n0 + srow + 64) * ldb + skc;

    int fsw = (l15 >> 1) & 3;                          // fragment-read column swizzle

    f32x4 acc[4][4];
    #pragma unroll
    for (int i = 0; i < 4; ++i)
        #pragma unroll
        for (int j = 0; j < 4; ++j)
            acc[i][j] = (f32x4){0.f, 0.f, 0.f, 0.f};

    gld_lds16(Ap,  &As[0][tid * 8]);
    gld_lds16(Ap2, &As[0][(tid + 256) * 8]);
    gld_lds16(Bp,  &Bs[0][tid * 8]);
    gld_lds16(Bp2, &Bs[0][(tid + 256) * 8]);

    int niter = K >> 5;
    for (int j = 0; j < niter; ++j) {
        __syncthreads();
        int p = j & 1;
        if (j + 1 < niter) {
            int k1 = (j + 1) << 5;
            gld_lds16(Ap  + k1, &As[p ^ 1][tid * 8]);
            gld_lds16(Ap2 + k1, &As[p ^ 1][(tid + 256) * 8]);
            gld_lds16(Bp  + k1, &Bs[p ^ 1][tid * 8]);
            gld_lds16(Bp2 + k1, &Bs[p ^ 1][(tid + 256) * 8]);
        }
        short8 a[4], b[4];
        #pragma unroll
        for (int i = 0; i < 4; ++i) {
            a[i] = *(const short8*)&As[p][(wm + i * 16 + l15) * 32 + (quad ^ fsw) * 8];
            b[i] = *(const short8*)&Bs[p][(wn + i * 16 + l15) * 32 + (quad ^ fsw) * 8];
        }
        #pragma unroll
        for (int i = 0; i < 4; ++i)
            #pragma unroll
            for (int jj = 0; jj < 4; ++jj)
                acc[i][jj] = __builtin_amdgcn_mfma_f32_16x16x32_bf16(a[i], b[jj], acc[i][jj], 0, 0, 0);
    }

    #pragma unroll
    for (int i = 0; i < 4; ++i) {
        int rBase = m0 + wm + i * 16 + quad * 4;
        #pragma unroll
        for (int j = 0; j < 4; ++j) {
            int col = n0 + wn + j * 16 + l15;
            float bv = bias ? bias[col] : 0.f;
            #pragma unroll
            for (int r = 0; r < 4; ++r) {
                int rowg = rBase + r;
                float v = acc[i][j][r] + bv;
                if (DO_GELU) v = gelu_exact(v);
                if (RES_MODE == 1) v += ((const float*)res)[(size_t)rowg * ldres + col];
                if (RES_MODE == 2) v += bf2f(((const ushort_t*)res)[(size_t)rowg * ldres + col]);
                if (OUT_MODE == 0)
                    ((float*)Cv)[(size_t)rowg * ldc + col] = v;
                else
                    ((ushort_t*)Cv)[(size_t)rowg * ldc + col] = f2bf(v);
            }
        }
    }
}

// ---------------------------------------------------------------- bf16 MFMA GEMM, intra-block split-K, BK=64
// 512 thr = 2 groups x 4 waves; each group: own K-half, own dbuf (A 16KB + B 16KB per buffer),
// 128KB LDS total (gfx950: 160KB/workgroup). BK=64 halves barrier count vs R8 (64->32 for
// K=4096) so the per-barrier vmcnt(0)-drain latency is amortized over 2x compute.
template<int OUT_MODE, bool DO_GELU, int RES_MODE>
__global__ __launch_bounds__(512, 1) void mfma_gemm_sk(
    const ushort_t* __restrict__ A, int lda,
    const ushort_t* __restrict__ Bt, int ldb,
    void* __restrict__ Cv, int ldc, int K,
    const float* __restrict__ bias,
    const void* __restrict__ res, int ldres) {

    __shared__ ushort_t Smem[65536];    // 128KB
    #define SA_(g, p) (Smem + ((g) * 2 + (p)) * 8192)
    #define SB_(g, p) (Smem + 32768 + ((g) * 2 + (p)) * 8192)

    int tid  = threadIdx.x;
    int lane = tid & 63;
    int wave = tid >> 6;
    int g = wave >> 2, w = wave & 3;
    int m0, n0;
    swizzle_mn(m0, n0);
    int wm = (w & 1) * 64, wn = (w >> 1) * 64;
    int quad = lane >> 4, l15 = lane & 15;

    int lt = tid & 255;
    int srow = lt >> 3;                            // 0..31 (row within 32-row chunk group)
    int gp8  = ((lt & 7) ^ (srow & 7)) * 8;        // swizzled global k-part (n*32 preserves &7)
    int kbase = g * (K >> 1);
    const ushort_t* ApB = A  + (size_t)m0 * lda + kbase + gp8;
    const ushort_t* BpB = Bt + (size_t)n0 * ldb + kbase + gp8;

    f32x4 acc[4][4];
    #pragma unroll
    for (int i = 0; i < 4; ++i)
        #pragma unroll
        for (int j = 0; j < 4; ++j)
            acc[i][j] = (f32x4){0.f, 0.f, 0.f, 0.f};

    // prologue: stage tile 0 (A/B 128x64 each, chunks c = n*256+lt)
    #pragma unroll
    for (int n = 0; n < 4; ++n) {
        int row = n * 32 + srow;
        gld_lds16(ApB + (size_t)row * lda, SA_(g, 0) + (n * 256 + lt) * 8);
        gld_lds16(BpB + (size_t)row * ldb, SB_(g, 0) + (n * 256 + lt) * 8);
    }

    int niter = K >> 7;                 // per group: K/2 over BK=64
    for (int j = 0; j < niter; ++j) {
        __syncthreads();
        int p = j & 1;
        if (j + 1 < niter) {
            int k1 = (j + 1) << 6;
            #pragma unroll
            for (int n = 0; n < 4; ++n) {
                int row = n * 32 + srow;
                gld_lds16(ApB + (size_t)row * lda + k1, SA_(g, p ^ 1) + (n * 256 + lt) * 8);
                gld_lds16(BpB + (size_t)row * ldb + k1, SB_(g, p ^ 1) + (n * 256 + lt) * 8);
            }
        }
        const ushort_t* Ac = SA_(g, p);
        const ushort_t* Bc = SB_(g, p);
        #pragma unroll
        for (int kk = 0; kk < 2; ++kk) {
            short8 a[4], b[4];
            #pragma unroll
            for (int i = 0; i < 4; ++i) {
                int ra = wm + i * 16 + l15;
                int rb = wn + i * 16 + l15;
                a[i] = *(const short8*)(Ac + ra * 64 + (((kk * 4 + quad) ^ (ra & 7))) * 8);
                b[i] = *(const short8*)(Bc + rb * 64 + (((kk * 4 + quad) ^ (rb & 7))) * 8);
            }
            #pragma unroll
            for (int i = 0; i < 4; ++i)
                #pragma unroll
                for (int jj = 0; jj < 4; ++jj)
                    acc[i][jj] = __builtin_amdgcn_mfma_f32_16x16x32_bf16(a[i], b[jj], acc[i][jj], 0, 0, 0);
        }
    }

    // cross-group reduction through dead staging LDS (64KB of the 128)
    __syncthreads();
    float* R = (float*)Smem;
    if (g == 1) {
        #pragma unroll
        for (int i = 0; i < 4; ++i)
            #pragma unroll
            for (int j = 0; j < 4; ++j)
                *(f32x4*)&R[(((w * 16 + i * 4 + j) * 64) + lane) * 4] = acc[i][j];
    }
    __syncthreads();
    if (g == 0) {
        #pragma unroll
        for (int i = 0; i < 4; ++i) {
            int rBase = m0 + wm + i * 16 + quad * 4;
            #pragma unroll
            for (int j = 0; j < 4; ++j) {
                f32x4 other = *(const f32x4*)&R[(((w * 16 + i * 4 + j) * 64) + lane) * 4];
                int col = n0 + wn + j * 16 + l15;
                float bv = bias ? bias[col] : 0.f;
                #pragma unroll
                for (int r = 0; r < 4; ++r) {
                    int rowg = rBase + r;
                    float v = acc[i][j][r] + other[r] + bv;
                    if (DO_GELU) v = gelu_exact(v);
                    if (RES_MODE == 1) v += ((const float*)res)[(size_t)rowg * ldres + col];
                    if (RES_MODE == 2) v += bf2f(((const ushort_t*)res)[(size_t)rowg * ldres + col]);
                    if (OUT_MODE == 0)
                        ((float*)Cv)[(size_t)rowg * ldc + col] = v;
                    else
                        ((ushort_t*)Cv)[(size_t)rowg * ldc + col] = f2bf(v);
                }
            }
        }
    }
    #undef SA_
    #undef SB_
}

// ---------------------------------------------------------------- QKV GEMM v3: bf16 out, head-major, Q pre-scaled
__global__ __launch_bounds__(256, 4) void mfma_gemm_qkv(
    const ushort_t* __restrict__ A, const ushort_t* __restrict__ Bt,
    ushort_t* __restrict__ Qh, ushort_t* __restrict__ Kh, ushort_t* __restrict__ Vh,
    const float* __restrict__ bias) {

    const int lda = 1024, ldb = 1024, K = 1024;
    __shared__ ushort_t As[2][128 * 32];
    __shared__ ushort_t Bs[2][128 * 32];

    int tid  = threadIdx.x;
    int lane = tid & 63;
    int m0, n0;
    swizzle_mn(m0, n0);
    int wave = tid >> 6;
    int wm = (wave & 1) * 64, wn = (wave >> 1) * 64;
    int quad = lane >> 4, l15 = lane & 15;

    int srow = tid >> 2;
    int skc  = (((tid & 3) ^ ((tid >> 3) & 3))) * 8;
    const ushort_t* Ap  = A  + (size_t)(m0 + srow)      * lda + skc;
    const ushort_t* Ap2 = A  + (size_t)(m0 + srow + 64) * lda + skc;
    const ushort_t* Bp  = Bt + (size_t)(n0 + srow)      * ldb + skc;
    const ushort_t* Bp2 = Bt + (size_t)(n0 + srow + 64) * ldb + skc;

    int fsw = (l15 >> 1) & 3;

    f32x4 acc[4][4];
    #pragma unroll
    for (int i = 0; i < 4; ++i)
        #pragma unroll
        for (int j = 0; j < 4; ++j)
            acc[i][j] = (f32x4){0.f, 0.f, 0.f, 0.f};

    gld_lds16(Ap,  &As[0][tid * 8]);
    gld_lds16(Ap2, &As[0][(tid + 256) * 8]);
    gld_lds16(Bp,  &Bs[0][tid * 8]);
    gld_lds16(Bp2, &Bs[0][(tid + 256) * 8]);

    const int niter = K >> 5;
    for (int j = 0; j < niter; ++j) {
        __syncthreads();
        int p = j & 1;
        if (j + 1 < niter) {
            int k1 = (j + 1) << 5;
            gld_lds16(Ap  + k1, &As[p ^ 1][tid * 8]);
            gld_lds16(Ap2 + k1, &As[p ^ 1][(tid + 256) * 8]);
            gld_lds16(Bp  + k1, &Bs[p ^ 1][tid * 8]);
            gld_lds16(Bp2 + k1, &Bs[p ^ 1][(tid + 256) * 8]);
        }
        short8 a[4], b[4];
        #pragma unroll
        for (int i = 0; i < 4; ++i) {
            a[i] = *(const short8*)&As[p][(wm + i * 16 + l15) * 32 + (quad ^ fsw) * 8];
            b[i] = *(const short8*)&Bs[p][(wn + i * 16 + l15) * 32 + (quad ^ fsw) * 8];
        }
        #pragma unroll
        for (int i = 0; i < 4; ++i)
            #pragma unroll
            for (int jj = 0; jj < 4; ++jj)
                acc[i][jj] = __builtin_amdgcn_mfma_f32_16x16x32_bf16(a[i], b[jj], acc[i][jj], 0, 0, 0);
    }

    #pragma unroll
    for (int i = 0; i < 4; ++i) {
        int rBase = m0 + wm + i * 16 + quad * 4;
        #pragma unroll
        for (int j = 0; j < 4; ++j) {
            int col = n0 + wn + j * 16 + l15;
            int sel = col >> 10;                    // 0=Q,1=K,2=V
            int h   = (col >> 6) & 15;
            int dh  = col & 63;
            ushort_t* dst = (sel == 0) ? Qh : (sel == 1 ? Kh : Vh);
            float sc = (sel == 0) ? QSCALE_F : 1.0f;
            float bv = bias[col];
            #pragma unroll
            for (int r = 0; r < 4; ++r) {
                int rowg = rBase + r;               // token
                int bb = rowg >> 11, s = rowg & 2047;
                float v = (acc[i][j][r] + bv) * sc;
                dst[((size_t)(bb * 16 + h) * S_LEN + s) * 64 + dh] = f2bf(v);
            }
        }
    }
}

// ---------------------------------------------------------------- fused flash attention v2 (unchanged)
__global__ __launch_bounds__(256, 4) void flash_kernel(
    const ushort_t* __restrict__ Qh, const ushort_t* __restrict__ Kh,
    const ushort_t* __restrict__ Vt, ushort_t* __restrict__ Z) {

    __shared__ ushort_t Klds[2][64 * 64];
    __shared__ ushort_t Vlds[2][64 * 64];
    __shared__ ushort_t Plds[4][16 * 64];

    int pair = blockIdx.x;                    // 0..31  (pair%8 keys XCD -> 2MB KV per XCD L2)
    int qt   = blockIdx.y;                    // 0..31
    int q0   = qt * 64;
    int tid = threadIdx.x, lane = tid & 63, wave = tid >> 6;
    int quad = lane >> 4, l15 = lane & 15;

    const ushort_t* Qbase = Qh + (size_t)pair * (S_LEN * 64);
    const ushort_t* Kbase = Kh + (size_t)pair * (S_LEN * 64);
    const ushort_t* Vbase = Vt + (size_t)pair * (S_LEN * 64);
    ushort_t* Qstage = &Plds[0][0];

    #pragma unroll
    for (int n = 0; n < 2; ++n) {
        int c = tid + n * 256;
        int row = c >> 3, part = c & 7;
        gld_lds16(Qbase + (size_t)(q0 + row) * 64 + ((part ^ (row & 7)) * 8), Qstage + c * 8);
    }
    __syncthreads();
    short8 qa[2];
    #pragma unroll
    for (int h = 0; h < 2; ++h) {
        int row = wave * 16 + l15;
        int part = (h * 4 + quad) ^ (row & 7);
        qa[h] = *(const short8*)(Qstage + row * 64 + part * 8);
    }

    f32x4 ls = (f32x4){0.f, 0.f, 0.f, 0.f};
    f32x4 zacc[4];
    #pragma unroll
    for (int dht = 0; dht < 4; ++dht) zacc[dht] = (f32x4){0.f, 0.f, 0.f, 0.f};

    #pragma unroll
    for (int n = 0; n < 2; ++n) {
        int c = tid + n * 256;
        int row = c >> 3, part = c & 7;
        int gp = (part ^ (row & 7)) * 8;
        gld_lds16(Kbase + (size_t)row * 64 + gp, &Klds[0][0] + c * 8);
        gld_lds16(Vbase + (size_t)row * S_LEN + gp, &Vlds[0][0] + c * 8);
    }

    for (int j = 0; j <= qt; ++j) {
        __syncthreads();
        int p = j & 1;
        if (j < qt) {
            int k1 = (j + 1) * 64;
            #pragma unroll
            for (int n = 0; n < 2; ++n) {
                int c = tid + n * 256;
                int row = c >> 3, part = c & 7;
                int gp = (part ^ (row & 7)) * 8;
                gld_lds16(Kbase + (size_t)(k1 + row) * 64 + gp, &Klds[p ^ 1][0] + c * 8);
                gld_lds16(Vbase + (size_t)row * S_LEN + k1 + gp, &Vlds[p ^ 1][0] + c * 8);
            }
        }
        const ushort_t* Kc = &Klds[p][0];
        const ushort_t* Vc = &Vlds[p][0];

        f32x4 s[4];
        #pragma unroll
        for (int jt = 0; jt < 4; ++jt) {
            int krow = jt * 16 + l15;
            int sw = krow & 7;
            short8 kb0 = *(const short8*)(Kc + krow * 64 + ((quad ^ sw) * 8));
            short8 kb1 = *(const short8*)(Kc + krow * 64 + (((quad + 4) ^ sw) * 8));
            f32x4 t = __builtin_amdgcn_mfma_f32_16x16x32_bf16(qa[0], kb0,
                        (f32x4){0.f, 0.f, 0.f, 0.f}, 0, 0, 0);
            s[jt] = __builtin_amdgcn_mfma_f32_16x16x32_bf16(qa[1], kb1, t, 0, 0, 0);
        }

        if (j == qt) {
            #pragma unroll
            for (int jt = 0; jt < 4; ++jt) {
                int kc = jt * 16 + l15;
                int qr = wave * 16 + quad * 4;
                #pragma unroll
                for (int r = 0; r < 4; ++r)
                    if (kc > qr + r) s[jt][r] = -1e30f;
            }
        }

        #pragma unroll
        for (int jt = 0; jt < 4; ++jt) {
            #pragma unroll
            for (int r = 0; r < 4; ++r) {
                float pv = exp2f(s[jt][r]);
                s[jt][r] = pv;
                ls[r] += pv;
            }
        }

        ushort_t* Pw = &Plds[wave][0];
        #pragma unroll
        for (int jt = 0; jt < 4; ++jt) {
            int col = jt * 16 + l15;
            int cp = col >> 3, ci = col & 7;
            #pragma unroll
            for (int r = 0; r < 4; ++r) {
                int prow = quad * 4 + r;
                Pw[prow * 64 + ((cp ^ (prow & 7)) * 8) + ci] = f2bf(s[jt][r]);
            }
        }

        #pragma unroll
        for (int kc = 0; kc < 2; ++kc) {
            int prow = l15;
            short8 pa = *(const short8*)(Pw + prow * 64 + ((((kc * 4 + quad) ^ (prow & 7))) * 8));
            #pragma unroll
            for (int dht = 0; dht < 4; ++dht) {
                int vrow = dht * 16 + l15;
                short8 vb = *(const short8*)(Vc + vrow * 64 + ((((kc * 4 + quad) ^ (vrow & 7))) * 8));
                zacc[dht] = __builtin_amdgcn_mfma_f32_16x16x32_bf16(pa, vb, zacc[dht], 0, 0, 0);
            }
        }
    }

    #pragma unroll
    for (int d = 1; d < 16; d <<= 1) {
        ls[0] += __shfl_xor(ls[0], d, 64);
        ls[1] += __shfl_xor(ls[1], d, 64);
        ls[2] += __shfl_xor(ls[2], d, 64);
        ls[3] += __shfl_xor(ls[3], d, 64);
    }
    int bb = pair >> 4, h = pair & 15;
    #pragma unroll
    for (int r = 0; r < 4; ++r) {
        int qrow = q0 + wave * 16 + quad * 4 + r;
        size_t tok = (size_t)bb * S_LEN + qrow;
        float inv = 1.0f / ls[r];
        #pragma unroll
        for (int dht = 0; dht < 4; ++dht)
            Z[tok * D_MODEL + h * 64 + dht * 16 + l15] = f2bf(zacc[dht][r] * inv);
    }
}

// ---------------------------------------------------------------- launch
extern "C" void kernel_launch(void* const* d_in, const int* in_sizes, int n_in,
                              void* d_out, int out_size, void* d_ws, size_t ws_size,
                              hipStream_t stream) {
    const float* resid_pre = (const float*)d_in[0];
    const float* ln1_w = (const float*)d_in[1];
    const float* ln1_b = (const float*)d_in[2];
    const float* W_Q   = (const float*)d_in[3];
    const float* b_Q   = (const float*)d_in[4];
    const float* W_K   = (const float*)d_in[5];
    const float* b_K   = (const float*)d_in[6];
    const float* W_V   = (const float*)d_in[7];
    const float* b_V   = (const float*)d_in[8];
    const float* W_O   = (const float*)d_in[9];
    const float* b_O   = (const float*)d_in[10];
    const float* ln2_w = (const float*)d_in[11];
    const float* ln2_b = (const float*)d_in[12];
    const float* W_in  = (const float*)d_in[13];
    const float* b_in  = (const float*)d_in[14];
    const float* W_out = (const float*)d_in[15];
    const float* b_out = (const float*)d_in[16];
    float* out = (float*)d_out;
    char* W = (char*)d_ws;

    const size_t MB = 1u << 20;
    ushort_t* Qh     = (ushort_t*)(W + 0 * MB);      // [32][2048][64]  8MB
    ushort_t* Kh     = (ushort_t*)(W + 8 * MB);      // 8MB
    ushort_t* Vh     = (ushort_t*)(W + 16 * MB);     // 8MB
    ushort_t* Vt     = (ushort_t*)(W + 24 * MB);     // [32][64][2048]  8MB
    ushort_t* Zbf    = (ushort_t*)(W + 32 * MB);     // [4096][1024]    8MB
    ushort_t* LN1a   = (ushort_t*)(W + 40 * MB);     // 8MB
    ushort_t* Wqkv   = (ushort_t*)(W + 48 * MB);     // [3072][1024]    6MB
    ushort_t* Wo_t   = (ushort_t*)(W + 54 * MB);     // 2MB
    ushort_t* Win_t  = (ushort_t*)(W + 56 * MB);     // 8MB
    ushort_t* Wout_t = (ushort_t*)(W + 64 * MB);     // 8MB
    ushort_t* LN2a   = (ushort_t*)(W + 72 * MB);     // 8MB
    ushort_t* MLPh   = (ushort_t*)(W + 80 * MB);     // [4096][4096]    32MB
    ushort_t* MIDb   = (ushort_t*)(W + 112 * MB);    // bf16 resid_mid  8MB
    float*    qbias  = (float*)  (W + 128 * MB);     // 12KB

    dim3 tb(32, 8);

    // ---- fused weight prep (5 transposes + bias concat) + LN1 ----
    prep_weights<<<12300, 256, 0, stream>>>(W_Q, W_K, W_V, W_O, W_in, W_out,
                                            b_Q, b_K, b_V,
                                            Wqkv, Wo_t, Win_t, Wout_t, qbias);
    ln_kernel<<<T_TOKENS, 256, 0, stream>>>(resid_pre, ln1_w, ln1_b, LN1a);

    // ---- QKV projection -> head-major bf16 (Q pre-scaled) ----
    mfma_gemm_qkv<<<dim3(24, 32), 256, 0, stream>>>(LN1a, Wqkv, Qh, Kh, Vh, qbias);
    tpose_b2b<<<dim3(64, 2, 32), tb, 0, stream>>>(Vh, Vt);

    // ---- fused flash attention ----
    flash_kernel<<<dim3(32, 32), 256, 0, stream>>>(Qh, Kh, Vt, Zbf);

    // ---- O-proj + residual(resid_pre fp32) -> MIDb (bf16) ----
    mfma_gemm_sk<1, false, 1><<<dim3(8, 32), 512, 0, stream>>>(
        Zbf, 1024, Wo_t, 1024, MIDb, 1024, 1024, b_O, resid_pre, 1024);

    // ---- LN2 (bf16 in) + MLP ----
    ln_kernel_b<<<T_TOKENS, 256, 0, stream>>>(MIDb, ln2_w, ln2_b, LN2a);
    mfma_gemm<1, true, 0><<<dim3(32, 32), 256, 0, stream>>>(
        LN2a, 1024, Win_t, 1024, MLPh, 4096, 1024, b_in, nullptr, 0);
    mfma_gemm_sk<0, false, 2><<<dim3(8, 32), 512, 0, stream>>>(
        MLPh, 4096, Wout_t, 4096, out, 1024, 4096, b_out, MIDb, 1024);
}